// Round 4
// baseline (1797.907 us; speedup 1.0000x reference)
//
#include <hip/hip_runtime.h>

#define V_DIM 128256
#define K_DIM 2048
#define M_DIM 2048
#define NPB (V_DIM / 256)  // 501 vocab blocks of 256
#define NT (K_DIM / 64)    // 32 K-tiles

using f32x4  = __attribute__((ext_vector_type(4))) float;
using bf16x8 = __attribute__((ext_vector_type(8))) short;

// round-to-nearest-even f32 -> bf16 (as ushort)
static __device__ __forceinline__ unsigned short f2b(float f) {
  unsigned int x = __float_as_uint(f);
  unsigned int r = (x + 0x7fffu + ((x >> 16) & 1u)) >> 16;
  return (unsigned short)r;
}

// ---------------- x f32 -> bf16 ----------------
__global__ __launch_bounds__(256) void cvt_x(const float* __restrict__ x,
                                             unsigned short* __restrict__ xb) {
  const size_t i = ((size_t)blockIdx.x * 256 + threadIdx.x) * 8;
  const float4 a = *(const float4*)&x[i];
  const float4 b = *(const float4*)&x[i + 4];
  union { unsigned short u[8]; uint4 v; } o;
  o.u[0] = f2b(a.x); o.u[1] = f2b(a.y); o.u[2] = f2b(a.z); o.u[3] = f2b(a.w);
  o.u[4] = f2b(b.x); o.u[5] = f2b(b.y); o.u[6] = f2b(b.z); o.u[7] = f2b(b.w);
  *(uint4*)&xb[i] = o.v;
}

// ---------------- W transpose: [K][V] f32 -> [V][K] bf16 ----------------
__global__ __launch_bounds__(256) void transpose_w(const float* __restrict__ wgt,
                                                   unsigned short* __restrict__ wtc,
                                                   int c0) {
  __shared__ unsigned short tile[64][65];
  const int t  = threadIdx.x;
  const int cb = blockIdx.x * 64;
  const int kb = blockIdx.y * 64;
  const int tc4 = (t & 15) * 4;
  const int tk  = t >> 4;
#pragma unroll
  for (int p = 0; p < 4; ++p) {
    const int k = kb + tk + p * 16;
    const float4 v = *(const float4*)&wgt[(size_t)k * V_DIM + (c0 + cb + tc4)];
    tile[tc4 + 0][tk + p * 16] = f2b(v.x);
    tile[tc4 + 1][tk + p * 16] = f2b(v.y);
    tile[tc4 + 2][tk + p * 16] = f2b(v.z);
    tile[tc4 + 3][tk + p * 16] = f2b(v.w);
  }
  __syncthreads();
  const int wk4 = (t & 15) * 4;
  const int wc  = t >> 4;
#pragma unroll
  for (int p = 0; p < 4; ++p) {
    const int c = wc + p * 16;
    ushort4 o;
    o.x = tile[c][wk4 + 0];
    o.y = tile[c][wk4 + 1];
    o.z = tile[c][wk4 + 2];
    o.w = tile[c][wk4 + 3];
    *(ushort4*)&wtc[(size_t)(cb + c) * K_DIM + (kb + wk4)] = o;
  }
}

// ---------------- 256x256 pipelined GEMM + partial sum-of-exp ----------------
// Schedule: 4 phases/tile, ds_reads issued one phase ahead (hidden under MFMA),
// counted lgkmcnt waits, 5 barriers/tile, vmcnt(6) once/tile.
// Stage ledger (per wave): ph0 +2 (t+1 Q3/I3 -> c^1), ph1..3 +2 each (t+2 q-1 -> c).
// At ph3 vmcnt(6): retires ph0 pair => tile t+1 fully resident before pre-reads.
#define MF(a, b, c) __builtin_amdgcn_mfma_f32_16x16x32_bf16(a, b, c, 0, 0, 0)

#define STAGE_A(T, q, d) do {                                                   \
    const int rb_ = 32 * (q) + (w & 3) * 8 + (w >> 2) * 128;                    \
    __builtin_amdgcn_global_load_lds(                                           \
        (const __attribute__((address_space(1))) void*)                         \
            &xb[(size_t)(m0 + rb_ + lr) * K_DIM + (T) * 64 + sw8],              \
        (__attribute__((address_space(3))) void*)&Al[d][rb_ * 64], 16, 0, 0);   \
  } while (0)

#define STAGE_B(T, i, d) do {                                                   \
    const int rb_ = (i) * 64 + w * 8;                                           \
    __builtin_amdgcn_global_load_lds(                                           \
        (const __attribute__((address_space(1))) void*)                         \
            &wt[(size_t)(n0 + rb_ + lr) * K_DIM + (T) * 64 + sw8],              \
        (__attribute__((address_space(3))) void*)&Bl[d][rb_ * 64], 16, 0, 0);   \
  } while (0)

#define RD_A(c, mi, s) (*(const bf16x8*)&Al[c][(wm * 128 + (mi) * 16 + (l & 15)) * 64 + \
                                               ((((s) * 4 + (l >> 4)) ^ (l & 7)) * 8)])
#define RD_B(c, ni, s) (*(const bf16x8*)&Bl[c][(wn * 64 + (ni) * 16 + (l & 15)) * 64 + \
                                               ((((s) * 4 + (l >> 4)) ^ (l & 7)) * 8)])

// 8 independent MFMAs: acc[2q..2q+1][*] += Afrag(s) * B(s)
#define MFMA_S(q, s, A0, A1)                                       \
  acc[2*(q)][0]   = MF(A0, bfr[0][s], acc[2*(q)][0]);              \
  acc[2*(q)+1][0] = MF(A1, bfr[0][s], acc[2*(q)+1][0]);            \
  acc[2*(q)][1]   = MF(A0, bfr[1][s], acc[2*(q)][1]);              \
  acc[2*(q)+1][1] = MF(A1, bfr[1][s], acc[2*(q)+1][1]);            \
  acc[2*(q)][2]   = MF(A0, bfr[2][s], acc[2*(q)][2]);              \
  acc[2*(q)+1][2] = MF(A1, bfr[2][s], acc[2*(q)+1][2]);            \
  acc[2*(q)][3]   = MF(A0, bfr[3][s], acc[2*(q)][3]);              \
  acc[2*(q)+1][3] = MF(A1, bfr[3][s], acc[2*(q)+1][3]);

#define LGKM(n) asm volatile("s_waitcnt lgkmcnt(" #n ")" ::: "memory"); \
                __builtin_amdgcn_sched_barrier(0)

__global__ __launch_bounds__(512, 2) void gemm_lse(const unsigned short* __restrict__ xb,
                                                   const unsigned short* __restrict__ wt,
                                                   float* __restrict__ partial,
                                                   int vb0, int nbx) {
  __shared__ unsigned short Al[2][256 * 64];
  __shared__ unsigned short Bl[2][256 * 64];

  const int tid = threadIdx.x;
  const int w = tid >> 6, l = tid & 63;
  const int wm = w >> 2, wn = w & 3;

  // bijective XCD swizzle (nwg = nbx*8, always %8==0); 8 consecutive share B-panel
  const int nwg = nbx * 8;
  const int swz = (blockIdx.x & 7) * (nwg >> 3) + (blockIdx.x >> 3);
  const int m0 = (swz & 7) * 256;
  const int n0 = (swz >> 3) * 256;

  const int lr = l >> 3;
  const int sw8 = ((l & 7) ^ lr) * 8;

  f32x4 acc[8][4] = {};
  bf16x8 bfr[4][2];                 // current tile's B (s0 copied from bnx)
  bf16x8 bnx0, bnx1, bnx2, bnx3;    // next tile's B s0 (pre-read at ph3)
  bf16x8 a00, a01, a02, a03;        // quarter 0 frags (mi 0,1 x s0,s1)
  bf16x8 a10, a11, a12, a13;        // quarter 1 (mi 2,3)
  bf16x8 a20, a21, a22, a23;        // quarter 2 (mi 4,5)
  bf16x8 a30, a31, a32, a33;        // quarter 3 (mi 6,7)

  // prologue: tile0 full (8 stages) + tile1 q0-2/I0-2 (6 stages)
  STAGE_A(0, 0, 0); STAGE_A(0, 1, 0); STAGE_A(0, 2, 0); STAGE_A(0, 3, 0);
  STAGE_B(0, 0, 0); STAGE_B(0, 1, 0); STAGE_B(0, 2, 0); STAGE_B(0, 3, 0);
  STAGE_A(1, 0, 1); STAGE_B(1, 0, 1);
  STAGE_A(1, 1, 1); STAGE_B(1, 1, 1);
  STAGE_A(1, 2, 1); STAGE_B(1, 2, 1);
  asm volatile("s_waitcnt vmcnt(6)" ::: "memory");  // tile0 resident
  __builtin_amdgcn_s_barrier();
  // pre-read tile0: A q0 + B s0
  a00 = RD_A(0, 0, 0); a01 = RD_A(0, 0, 1); a02 = RD_A(0, 1, 0); a03 = RD_A(0, 1, 1);
  bnx0 = RD_B(0, 0, 0); bnx1 = RD_B(0, 1, 0); bnx2 = RD_B(0, 2, 0); bnx3 = RD_B(0, 3, 0);

#pragma unroll 1
  for (int t = 0; t < NT; ++t) {
    const int c = t & 1;
    // ================ phase 0 ================
    // issue B s1 (4), then A q1 (4); outstanding: pre-8 + 8
    bfr[0][1] = RD_B(c, 0, 1); bfr[1][1] = RD_B(c, 1, 1);
    bfr[2][1] = RD_B(c, 2, 1); bfr[3][1] = RD_B(c, 3, 1);
    asm volatile("" ::: "memory");  // keep Bs1 older than Aq1 for lgkm(4)
    a10 = RD_A(c, 2, 0); a11 = RD_A(c, 2, 1); a12 = RD_A(c, 3, 0); a13 = RD_A(c, 3, 1);
    if (t + 1 < NT) { STAGE_A(t + 1, 3, c ^ 1); STAGE_B(t + 1, 3, c ^ 1); }
    // adopt pre-read B s0 (compiler inserts the matching counted wait)
    bfr[0][0] = bnx0; bfr[1][0] = bnx1; bfr[2][0] = bnx2; bfr[3][0] = bnx3;
    LGKM(8);  // pre-8 (Aq0 + Bs0) retired; Bs1+Aq1 in flight
    __builtin_amdgcn_s_setprio(1);
    MFMA_S(0, 0, a00, a02);
    __builtin_amdgcn_s_setprio(0);
    LGKM(4);  // Bs1 retired; Aq1 in flight
    __builtin_amdgcn_s_setprio(1);
    MFMA_S(0, 1, a01, a03);
    __builtin_amdgcn_s_setprio(0);
    __builtin_amdgcn_s_barrier();
    // ================ phase 1 ================
    a20 = RD_A(c, 4, 0); a21 = RD_A(c, 4, 1); a22 = RD_A(c, 5, 0); a23 = RD_A(c, 5, 1);
    if (t + 2 < NT) { STAGE_A(t + 2, 0, c); STAGE_B(t + 2, 0, c); }
    LGKM(4);  // Aq1 retired; Aq2 in flight
    __builtin_amdgcn_s_setprio(1);
    MFMA_S(1, 0, a10, a12);
    MFMA_S(1, 1, a11, a13);
    __builtin_amdgcn_s_setprio(0);
    __builtin_amdgcn_s_barrier();
    // ================ phase 2 ================
    a30 = RD_A(c, 6, 0); a31 = RD_A(c, 6, 1); a32 = RD_A(c, 7, 0); a33 = RD_A(c, 7, 1);
    if (t + 2 < NT) { STAGE_A(t + 2, 1, c); STAGE_B(t + 2, 1, c); }
    LGKM(4);  // Aq2 retired; Aq3 in flight
    __builtin_amdgcn_s_setprio(1);
    MFMA_S(2, 0, a20, a22);
    MFMA_S(2, 1, a21, a23);
    __builtin_amdgcn_s_setprio(0);
    __builtin_amdgcn_s_barrier();
    // ================ phase 3 ================
    if (t + 2 < NT) { STAGE_A(t + 2, 2, c); STAGE_B(t + 2, 2, c); }
    if (t < NT - 2) asm volatile("s_waitcnt vmcnt(6)" ::: "memory");
    else            asm volatile("s_waitcnt vmcnt(0)" ::: "memory");
    __builtin_amdgcn_s_barrier();  // tile t+1 collectively resident
    if (t + 1 < NT) {
      // pre-read next tile: A q0 + B s0 from c^1 (lands under MFMA q3)
      a00 = RD_A(c ^ 1, 0, 0); a01 = RD_A(c ^ 1, 0, 1);
      a02 = RD_A(c ^ 1, 1, 0); a03 = RD_A(c ^ 1, 1, 1);
      bnx0 = RD_B(c ^ 1, 0, 0); bnx1 = RD_B(c ^ 1, 1, 0);
      bnx2 = RD_B(c ^ 1, 2, 0); bnx3 = RD_B(c ^ 1, 3, 0);
      LGKM(8);  // Aq3 retired; pre-8 in flight
    } else {
      LGKM(0);
    }
    __builtin_amdgcn_s_setprio(1);
    MFMA_S(3, 0, a30, a32);
    MFMA_S(3, 1, a31, a33);
    __builtin_amdgcn_s_setprio(0);
    __builtin_amdgcn_s_barrier();
  }

  // ---- epilogue: per-row sum of exp over this block's 256 cols ----
  // C layout: row = wm*128 + mi*16 + (l>>4)*4 + r ; col = wn*64 + ni*16 + (l&15)
  float rs[8][4];
#pragma unroll
  for (int mi = 0; mi < 8; ++mi)
#pragma unroll
    for (int r = 0; r < 4; ++r) {
      float s = 0.f;
#pragma unroll
      for (int ni = 0; ni < 4; ++ni)
        s += exp2f(acc[mi][ni][r] * 1.4426950408889634f);
#pragma unroll
      for (int off = 1; off <= 8; off <<= 1) s += __shfl_xor(s, off, 64);
      rs[mi][r] = s;
    }
  __syncthreads();
  float* red = (float*)&Al[0][0];  // [4 wn][256 rows]
  if ((l & 15) == 0) {
#pragma unroll
    for (int mi = 0; mi < 8; ++mi)
#pragma unroll
      for (int r = 0; r < 4; ++r)
        red[wn * 256 + wm * 128 + mi * 16 + (l >> 4) * 4 + r] = rs[mi][r];
  }
  __syncthreads();
  if (tid < 256) {
    const float tot = (red[tid] + red[256 + tid]) + (red[512 + tid] + red[768 + tid]);
    partial[(size_t)(m0 + tid) * NPB + (vb0 + (swz >> 3))] = tot;
  }
}

// ---------------- exact f32 target logit ----------------
__global__ __launch_bounds__(256) void target_dot(const float* __restrict__ x,
                                                  const float* __restrict__ wgt,
                                                  const int* __restrict__ labels,
                                                  float* __restrict__ tgt) {
  const int row = blockIdx.x;
  int lab = labels[row];
  lab = lab < 0 ? 0 : (lab >= V_DIM ? V_DIM - 1 : lab);
  float s = 0.f;
  for (int k = threadIdx.x; k < K_DIM; k += 256)
    s += x[(size_t)row * K_DIM + k] * wgt[(size_t)k * V_DIM + lab];
#pragma unroll
  for (int off = 1; off < 64; off <<= 1) s += __shfl_xor(s, off, 64);
  __shared__ float w4[4];
  if ((threadIdx.x & 63) == 0) w4[threadIdx.x >> 6] = s;
  __syncthreads();
  if (threadIdx.x == 0) tgt[row] = (w4[0] + w4[1]) + (w4[2] + w4[3]);
}

// ---------------- final reduce ----------------
__global__ __launch_bounds__(256) void reduce_lse(const float* __restrict__ partial,
                                                  const float* __restrict__ tgt,
                                                  const int* __restrict__ labels,
                                                  float* __restrict__ out) {
  const int row = blockIdx.x;
  float s = 0.f;
  for (int vb = threadIdx.x; vb < NPB; vb += 256)
    s += partial[(size_t)row * NPB + vb];
#pragma unroll
  for (int off = 1; off < 64; off <<= 1) s += __shfl_xor(s, off, 64);
  __shared__ float w4[4];
  if ((threadIdx.x & 63) == 0) w4[threadIdx.x >> 6] = s;
  __syncthreads();
  if (threadIdx.x == 0) {
    const float tot = (w4[0] + w4[1]) + (w4[2] + w4[3]);
    const float lse = logf(tot);
    const float loss = (labels[row] != -100) ? (lse - tgt[row]) : 0.f;
    out[row] = loss;
    out[M_DIM + row] = lse;
  }
}

extern "C" void kernel_launch(void* const* d_in, const int* in_sizes, int n_in,
                              void* d_out, int out_size, void* d_ws, size_t ws_size,
                              hipStream_t stream) {
  const float* x = (const float*)d_in[0];
  const float* wgt = (const float*)d_in[1];
  const int* labels = (const int*)d_in[2];
  float* out = (float*)d_out;

  char* ws = (char*)d_ws;
  unsigned short* xb = (unsigned short*)ws;
  size_t off = (size_t)M_DIM * K_DIM * 2;
  float* partial = (float*)(ws + off);
  off += (size_t)M_DIM * NPB * 4;
  float* tgt = (float*)(ws + off);
  off += (size_t)M_DIM * 4;
  off = (off + 255) & ~(size_t)255;
  unsigned short* wtc = (unsigned short*)(ws + off);
  const size_t avail = ws_size > off ? ws_size - off : 0;
  int CC = V_DIM;  // full-V transpose (needs 525 MB; ws is ~4.2 GB)
  if ((size_t)CC * K_DIM * 2 > avail) {
    CC = 16384;
    while (CC > 256 && (size_t)CC * K_DIM * 2 > avail) CC >>= 1;
  }

  cvt_x<<<dim3(M_DIM * K_DIM / (256 * 8)), dim3(256), 0, stream>>>(x, xb);
  target_dot<<<dim3(M_DIM), dim3(256), 0, stream>>>(x, wgt, labels, tgt);
  for (int c0 = 0; c0 < V_DIM; c0 += CC) {
    int cc = V_DIM - c0;
    if (cc > CC) cc = CC;
    transpose_w<<<dim3(cc / 64, K_DIM / 64), dim3(256), 0, stream>>>(wgt, wtc, c0);
    const int nbx = cc / 256;
    gemm_lse<<<dim3(nbx * 8), dim3(512), 0, stream>>>(xb, wtc, partial, c0 / 256, nbx);
  }
  reduce_lse<<<dim3(M_DIM), dim3(256), 0, stream>>>(partial, tgt, labels, out);
}

// Round 6
// 1643.324 us; speedup vs baseline: 1.0941x; 1.0941x over previous
//
#include <hip/hip_runtime.h>

#define V_DIM 128256
#define K_DIM 2048
#define M_DIM 2048
#define NPB (V_DIM / 256)  // 501 vocab blocks of 256
#define NT (K_DIM / 64)    // 32 K-tiles

using f32x4  = __attribute__((ext_vector_type(4))) float;
using bf16x8 = __attribute__((ext_vector_type(8))) short;

// round-to-nearest-even f32 -> bf16 (as ushort)
static __device__ __forceinline__ unsigned short f2b(float f) {
  unsigned int x = __float_as_uint(f);
  unsigned int r = (x + 0x7fffu + ((x >> 16) & 1u)) >> 16;
  return (unsigned short)r;
}

// ---------------- x f32 -> bf16 ----------------
__global__ __launch_bounds__(256) void cvt_x(const float* __restrict__ x,
                                             unsigned short* __restrict__ xb) {
  const size_t i = ((size_t)blockIdx.x * 256 + threadIdx.x) * 8;
  const float4 a = *(const float4*)&x[i];
  const float4 b = *(const float4*)&x[i + 4];
  union { unsigned short u[8]; uint4 v; } o;
  o.u[0] = f2b(a.x); o.u[1] = f2b(a.y); o.u[2] = f2b(a.z); o.u[3] = f2b(a.w);
  o.u[4] = f2b(b.x); o.u[5] = f2b(b.y); o.u[6] = f2b(b.z); o.u[7] = f2b(b.w);
  *(uint4*)&xb[i] = o.v;
}

// ---------------- W transpose: [K][V] f32 -> [V][K] bf16 ----------------
__global__ __launch_bounds__(256) void transpose_w(const float* __restrict__ wgt,
                                                   unsigned short* __restrict__ wtc,
                                                   int c0) {
  __shared__ unsigned short tile[64][65];
  const int t  = threadIdx.x;
  const int cb = blockIdx.x * 64;
  const int kb = blockIdx.y * 64;
  const int tc4 = (t & 15) * 4;
  const int tk  = t >> 4;
#pragma unroll
  for (int p = 0; p < 4; ++p) {
    const int k = kb + tk + p * 16;
    const float4 v = *(const float4*)&wgt[(size_t)k * V_DIM + (c0 + cb + tc4)];
    tile[tc4 + 0][tk + p * 16] = f2b(v.x);
    tile[tc4 + 1][tk + p * 16] = f2b(v.y);
    tile[tc4 + 2][tk + p * 16] = f2b(v.z);
    tile[tc4 + 3][tk + p * 16] = f2b(v.w);
  }
  __syncthreads();
  const int wk4 = (t & 15) * 4;
  const int wc  = t >> 4;
#pragma unroll
  for (int p = 0; p < 4; ++p) {
    const int c = wc + p * 16;
    ushort4 o;
    o.x = tile[c][wk4 + 0];
    o.y = tile[c][wk4 + 1];
    o.z = tile[c][wk4 + 2];
    o.w = tile[c][wk4 + 3];
    *(ushort4*)&wtc[(size_t)(cb + c) * K_DIM + (kb + wk4)] = o;
  }
}

// ---------------- 256x256 8-phase GEMM + partial sum-of-exp + target ----------------
// ROUND-3 PROVEN SKELETON (do not touch sync structure):
// 4 phases/tile: {ds-reads, 2x global_load_lds, [ph3: vmcnt(6)], barrier,
//                 lgkm(0), setprio(1), 16 MFMA, setprio(0), barrier}
#define MF(a, b, c) __builtin_amdgcn_mfma_f32_16x16x32_bf16(a, b, c, 0, 0, 0)

#define STAGE_A(T, q, d) do {                                                   \
    const int rb_ = 32 * (q) + (w & 3) * 8 + (w >> 2) * 128;                    \
    __builtin_amdgcn_global_load_lds(                                           \
        (const __attribute__((address_space(1))) void*)                         \
            &xb[(size_t)(m0 + rb_ + lr) * K_DIM + (T) * 64 + sw8],              \
        (__attribute__((address_space(3))) void*)&Al[d][rb_ * 64], 16, 0, 0);   \
  } while (0)

#define STAGE_B(T, i, d) do {                                                   \
    const int rb_ = (i) * 64 + w * 8;                                           \
    __builtin_amdgcn_global_load_lds(                                           \
        (const __attribute__((address_space(1))) void*)                         \
            &wt[(size_t)(n0 + rb_ + lr) * K_DIM + (T) * 64 + sw8],              \
        (__attribute__((address_space(3))) void*)&Bl[d][rb_ * 64], 16, 0, 0);   \
  } while (0)

#define RD_A(c, mi, s) (*(const bf16x8*)&Al[c][(wm * 128 + (mi) * 16 + (l & 15)) * 64 + \
                                               ((((s) * 4 + (l >> 4)) ^ (l & 7)) * 8)])
#define RD_B(c, ni, s) (*(const bf16x8*)&Bl[c][(wn * 64 + (ni) * 16 + (l & 15)) * 64 + \
                                               ((((s) * 4 + (l >> 4)) ^ (l & 7)) * 8)])

#define MFMA8(mi, aa0, aa1)                                        \
  acc[mi][0] = MF(aa0, bfr[0][0], acc[mi][0]);                     \
  acc[mi][0] = MF(aa1, bfr[0][1], acc[mi][0]);                     \
  acc[mi][1] = MF(aa0, bfr[1][0], acc[mi][1]);                     \
  acc[mi][1] = MF(aa1, bfr[1][1], acc[mi][1]);                     \
  acc[mi][2] = MF(aa0, bfr[2][0], acc[mi][2]);                     \
  acc[mi][2] = MF(aa1, bfr[2][1], acc[mi][2]);                     \
  acc[mi][3] = MF(aa0, bfr[3][0], acc[mi][3]);                     \
  acc[mi][3] = MF(aa1, bfr[3][1], acc[mi][3]);

#define PHASE(q) {                                                              \
    bf16x8 a0 = RD_A(cb, 2 * (q), 0), a1 = RD_A(cb, 2 * (q), 1);                \
    bf16x8 a2 = RD_A(cb, 2 * (q) + 1, 0), a3 = RD_A(cb, 2 * (q) + 1, 1);        \
    if (t + 2 < NT) { STAGE_A(t + 2, (q) - 1, cb); STAGE_B(t + 2, (q) - 1, cb); } \
    if ((q) == 3) {                                                             \
      if (t < NT - 2) asm volatile("s_waitcnt vmcnt(6)" ::: "memory");          \
      else            asm volatile("s_waitcnt vmcnt(0)" ::: "memory");          \
    }                                                                           \
    __builtin_amdgcn_s_barrier();                                               \
    asm volatile("s_waitcnt lgkmcnt(0)" ::: "memory");                          \
    __builtin_amdgcn_s_setprio(1);                                              \
    MFMA8(2 * (q), a0, a1);                                                     \
    MFMA8(2 * (q) + 1, a2, a3);                                                 \
    __builtin_amdgcn_s_setprio(0);                                              \
    __builtin_amdgcn_s_barrier();                                               \
  }

__global__ __launch_bounds__(512, 2) void gemm_lse(const unsigned short* __restrict__ xb,
                                                   const unsigned short* __restrict__ wt,
                                                   const int* __restrict__ labels,
                                                   float* __restrict__ partial,
                                                   float* __restrict__ tgt,
                                                   int c0, int nbx) {
  __shared__ unsigned short Al[2][256 * 64];
  __shared__ unsigned short Bl[2][256 * 64];
  __shared__ int larr[256];

  const int tid = threadIdx.x;
  const int w = tid >> 6, l = tid & 63;
  const int wm = w >> 2, wn = w & 3;

  // bijective XCD swizzle (nwg = nbx*8, always %8==0); 8 consecutive share B-panel
  const int nwg = nbx * 8;
  const int swz = (blockIdx.x & 7) * (nwg >> 3) + (blockIdx.x >> 3);
  const int m0 = (swz & 7) * 256;
  const int n0 = (swz >> 3) * 256;   // chunk-local
  const int gn0 = c0 + n0;           // global vocab col base

  const int lr = l >> 3;
  const int sw8 = ((l & 7) ^ lr) * 8;

  f32x4 acc[8][4] = {};
  bf16x8 bfr[4][2];

  if (tid < 256) larr[tid] = labels[m0 + tid];

  // prologue: tile0 fully + tile1 quarters/issues 0-2
  STAGE_A(0, 0, 0); STAGE_A(0, 1, 0); STAGE_A(0, 2, 0); STAGE_A(0, 3, 0);
  STAGE_B(0, 0, 0); STAGE_B(0, 1, 0); STAGE_B(0, 2, 0); STAGE_B(0, 3, 0);
  STAGE_A(1, 0, 1); STAGE_B(1, 0, 1);
  STAGE_A(1, 1, 1); STAGE_B(1, 1, 1);
  STAGE_A(1, 2, 1); STAGE_B(1, 2, 1);
  asm volatile("s_waitcnt vmcnt(6)" ::: "memory");
  __builtin_amdgcn_s_barrier();

#pragma unroll 1
  for (int t = 0; t < NT; ++t) {
    const int cb = t & 1;
    // ---- phase 0: load all B + A quarter 0; prefetch (t+1) Q3/I3 ----
    {
      bfr[0][0] = RD_B(cb, 0, 0); bfr[0][1] = RD_B(cb, 0, 1);
      bfr[1][0] = RD_B(cb, 1, 0); bfr[1][1] = RD_B(cb, 1, 1);
      bfr[2][0] = RD_B(cb, 2, 0); bfr[2][1] = RD_B(cb, 2, 1);
      bfr[3][0] = RD_B(cb, 3, 0); bfr[3][1] = RD_B(cb, 3, 1);
      bf16x8 a0 = RD_A(cb, 0, 0), a1 = RD_A(cb, 0, 1);
      bf16x8 a2 = RD_A(cb, 1, 0), a3 = RD_A(cb, 1, 1);
      if (t + 1 < NT) { STAGE_A(t + 1, 3, cb ^ 1); STAGE_B(t + 1, 3, cb ^ 1); }
      __builtin_amdgcn_s_barrier();
      asm volatile("s_waitcnt lgkmcnt(0)" ::: "memory");
      __builtin_amdgcn_s_setprio(1);
      MFMA8(0, a0, a1);
      MFMA8(1, a2, a3);
      __builtin_amdgcn_s_setprio(0);
      __builtin_amdgcn_s_barrier();
    }
    PHASE(1)
    PHASE(2)
    PHASE(3)
  }

  // ---- target extraction: thread slot (mi,ni,r) owns logit[row][col] ----
  // row = m0 + wm*128 + mi*16 + (l>>4)*4 + r ; col = gn0 + wn*64 + ni*16 + (l&15)
  {
    const int colbase = wn * 64 + (l & 15);
#pragma unroll
    for (int mi = 0; mi < 8; ++mi)
#pragma unroll
      for (int r = 0; r < 4; ++r) {
        const int row = wm * 128 + mi * 16 + (l >> 4) * 4 + r;
        int lab = larr[row];
        lab = lab < 0 ? 0 : (lab >= V_DIM ? V_DIM - 1 : lab);
        const int cl = lab - gn0;
#pragma unroll
        for (int ni = 0; ni < 4; ++ni)
          if (cl == colbase + ni * 16) tgt[m0 + row] = acc[mi][ni][r];
      }
  }

  // ---- epilogue: per-row sum of exp over this block's 256 cols ----
  float rs[8][4];
#pragma unroll
  for (int mi = 0; mi < 8; ++mi)
#pragma unroll
    for (int r = 0; r < 4; ++r) {
      float s = 0.f;
#pragma unroll
      for (int ni = 0; ni < 4; ++ni)
        s += exp2f(acc[mi][ni][r] * 1.4426950408889634f);
#pragma unroll
      for (int off = 1; off <= 8; off <<= 1) s += __shfl_xor(s, off, 64);
      rs[mi][r] = s;
    }
  __syncthreads();
  float* red = (float*)&Al[0][0];  // [4 wn][256 rows]
  if ((l & 15) == 0) {
#pragma unroll
    for (int mi = 0; mi < 8; ++mi)
#pragma unroll
      for (int r = 0; r < 4; ++r)
        red[wn * 256 + wm * 128 + mi * 16 + (l >> 4) * 4 + r] = rs[mi][r];
  }
  __syncthreads();
  if (tid < 256) {
    const float tot = (red[tid] + red[256 + tid]) + (red[512 + tid] + red[768 + tid]);
    partial[(size_t)(m0 + tid) * NPB + (c0 / 256 + (swz >> 3))] = tot;
  }
}

// ---------------- final reduce ----------------
__global__ __launch_bounds__(256) void reduce_lse(const float* __restrict__ partial,
                                                  const float* __restrict__ tgt,
                                                  const int* __restrict__ labels,
                                                  float* __restrict__ out) {
  const int row = blockIdx.x;
  float s = 0.f;
  for (int vb = threadIdx.x; vb < NPB; vb += 256)
    s += partial[(size_t)row * NPB + vb];
#pragma unroll
  for (int off = 1; off < 64; off <<= 1) s += __shfl_xor(s, off, 64);
  __shared__ float w4[4];
  if ((threadIdx.x & 63) == 0) w4[threadIdx.x >> 6] = s;
  __syncthreads();
  if (threadIdx.x == 0) {
    const float tot = (w4[0] + w4[1]) + (w4[2] + w4[3]);
    const float lse = logf(tot);
    const float loss = (labels[row] != -100) ? (lse - tgt[row]) : 0.f;
    out[row] = loss;
    out[M_DIM + row] = lse;
  }
}

extern "C" void kernel_launch(void* const* d_in, const int* in_sizes, int n_in,
                              void* d_out, int out_size, void* d_ws, size_t ws_size,
                              hipStream_t stream) {
  const float* x = (const float*)d_in[0];
  const float* wgt = (const float*)d_in[1];
  const int* labels = (const int*)d_in[2];
  float* out = (float*)d_out;

  char* ws = (char*)d_ws;
  unsigned short* xb = (unsigned short*)ws;
  size_t off = (size_t)M_DIM * K_DIM * 2;
  float* partial = (float*)(ws + off);
  off += (size_t)M_DIM * NPB * 4;
  float* tgt = (float*)(ws + off);
  off += (size_t)M_DIM * 4;
  off = (off + 255) & ~(size_t)255;
  unsigned short* wtc = (unsigned short*)(ws + off);
  const size_t avail = ws_size > off ? ws_size - off : 0;
  int CC = V_DIM;  // full-V transpose (needs 525 MB; ws is ~4.2 GB)
  if ((size_t)CC * K_DIM * 2 > avail) {
    CC = 16384;
    while (CC > 256 && (size_t)CC * K_DIM * 2 > avail) CC >>= 1;
  }

  cvt_x<<<dim3(M_DIM * K_DIM / (256 * 8)), dim3(256), 0, stream>>>(x, xb);
  for (int c0 = 0; c0 < V_DIM; c0 += CC) {
    int cc = V_DIM - c0;
    if (cc > CC) cc = CC;
    transpose_w<<<dim3(cc / 64, K_DIM / 64), dim3(256), 0, stream>>>(wgt, wtc, c0);
    const int nbx = cc / 256;
    gemm_lse<<<dim3(nbx * 8), dim3(512), 0, stream>>>(xb, wtc, labels, partial, tgt,
                                                      c0, nbx);
  }
  reduce_lse<<<dim3(M_DIM), dim3(256), 0, stream>>>(partial, tgt, labels, out);
}

// Round 7
// 1310.046 us; speedup vs baseline: 1.3724x; 1.2544x over previous
//
#include <hip/hip_runtime.h>

#define V_DIM 128256
#define K_DIM 2048
#define M_DIM 2048
#define NPB (V_DIM / 256)  // 501 vocab blocks of 256
#define NT (K_DIM / 64)    // 32 K-tiles

using f32x4  = __attribute__((ext_vector_type(4))) float;
using bf16x8 = __attribute__((ext_vector_type(8))) short;

// round-to-nearest-even f32 -> bf16 (as ushort)
static __device__ __forceinline__ unsigned short f2b(float f) {
  unsigned int x = __float_as_uint(f);
  unsigned int r = (x + 0x7fffu + ((x >> 16) & 1u)) >> 16;
  return (unsigned short)r;
}

// ---------------- x f32 -> bf16 ----------------
__global__ __launch_bounds__(256) void cvt_x(const float* __restrict__ x,
                                             unsigned short* __restrict__ xb) {
  const size_t i = ((size_t)blockIdx.x * 256 + threadIdx.x) * 8;
  const float4 a = *(const float4*)&x[i];
  const float4 b = *(const float4*)&x[i + 4];
  union { unsigned short u[8]; uint4 v; } o;
  o.u[0] = f2b(a.x); o.u[1] = f2b(a.y); o.u[2] = f2b(a.z); o.u[3] = f2b(a.w);
  o.u[4] = f2b(b.x); o.u[5] = f2b(b.y); o.u[6] = f2b(b.z); o.u[7] = f2b(b.w);
  *(uint4*)&xb[i] = o.v;
}

// ---------------- W chunk transpose: [K][V] f32 -> [cc][K] bf16 ----------------
__global__ __launch_bounds__(256) void transpose_w(const float* __restrict__ wgt,
                                                   unsigned short* __restrict__ wtc,
                                                   int c0) {
  __shared__ unsigned short tile[64][65];
  const int t  = threadIdx.x;
  const int cb = blockIdx.x * 64;
  const int kb = blockIdx.y * 64;
  const int tc4 = (t & 15) * 4;
  const int tk  = t >> 4;
#pragma unroll
  for (int p = 0; p < 4; ++p) {
    const int k = kb + tk + p * 16;
    const float4 v = *(const float4*)&wgt[(size_t)k * V_DIM + (c0 + cb + tc4)];
    tile[tc4 + 0][tk + p * 16] = f2b(v.x);
    tile[tc4 + 1][tk + p * 16] = f2b(v.y);
    tile[tc4 + 2][tk + p * 16] = f2b(v.z);
    tile[tc4 + 3][tk + p * 16] = f2b(v.w);
  }
  __syncthreads();
  const int wk4 = (t & 15) * 4;
  const int wc  = t >> 4;
#pragma unroll
  for (int p = 0; p < 4; ++p) {
    const int c = wc + p * 16;
    ushort4 o;
    o.x = tile[c][wk4 + 0];
    o.y = tile[c][wk4 + 1];
    o.z = tile[c][wk4 + 2];
    o.w = tile[c][wk4 + 3];
    *(ushort4*)&wtc[(size_t)(cb + c) * K_DIM + (kb + wk4)] = o;
  }
}

// ---------------- 256x256 8-phase GEMM + partial sum-of-exp + target ----------------
// ROUND-3 PROVEN BARRIER SKELETON. Round-7 change: phase 0's reads are split
// into two counted-lgkm halves (s0 cluster / s1 cluster) to halve the exposed
// LDS burst. Barrier placement identical to round 3.
#define MF(a, b, c) __builtin_amdgcn_mfma_f32_16x16x32_bf16(a, b, c, 0, 0, 0)

#define STAGE_A(T, q, d) do {                                                   \
    const int rb_ = 32 * (q) + (w & 3) * 8 + (w >> 2) * 128;                    \
    __builtin_amdgcn_global_load_lds(                                           \
        (const __attribute__((address_space(1))) void*)                         \
            &xb[(size_t)(m0 + rb_ + lr) * K_DIM + (T) * 64 + sw8],              \
        (__attribute__((address_space(3))) void*)&Al[d][rb_ * 64], 16, 0, 0);   \
  } while (0)

#define STAGE_B(T, i, d) do {                                                   \
    const int rb_ = (i) * 64 + w * 8;                                           \
    __builtin_amdgcn_global_load_lds(                                           \
        (const __attribute__((address_space(1))) void*)                         \
            &wt[(size_t)(n0 + rb_ + lr) * K_DIM + (T) * 64 + sw8],              \
        (__attribute__((address_space(3))) void*)&Bl[d][rb_ * 64], 16, 0, 0);   \
  } while (0)

#define RD_A(c, mi, s) (*(const bf16x8*)&Al[c][(wm * 128 + (mi) * 16 + (l & 15)) * 64 + \
                                               ((((s) * 4 + (l >> 4)) ^ (l & 7)) * 8)])
#define RD_B(c, ni, s) (*(const bf16x8*)&Bl[c][(wn * 64 + (ni) * 16 + (l & 15)) * 64 + \
                                               ((((s) * 4 + (l >> 4)) ^ (l & 7)) * 8)])

#define MFMA8(mi, aa0, aa1)                                        \
  acc[mi][0] = MF(aa0, bfr[0][0], acc[mi][0]);                     \
  acc[mi][0] = MF(aa1, bfr[0][1], acc[mi][0]);                     \
  acc[mi][1] = MF(aa0, bfr[1][0], acc[mi][1]);                     \
  acc[mi][1] = MF(aa1, bfr[1][1], acc[mi][1]);                     \
  acc[mi][2] = MF(aa0, bfr[2][0], acc[mi][2]);                     \
  acc[mi][2] = MF(aa1, bfr[2][1], acc[mi][2]);                     \
  acc[mi][3] = MF(aa0, bfr[3][0], acc[mi][3]);                     \
  acc[mi][3] = MF(aa1, bfr[3][1], acc[mi][3]);

// 8 MFMAs: acc[2q..2q+1][*] += Afrag(s) * B[*][s]
#define MFMA_HALF(q, s, A0, A1)                                    \
  acc[2*(q)][0]   = MF(A0, bfr[0][s], acc[2*(q)][0]);              \
  acc[2*(q)+1][0] = MF(A1, bfr[0][s], acc[2*(q)+1][0]);            \
  acc[2*(q)][1]   = MF(A0, bfr[1][s], acc[2*(q)][1]);              \
  acc[2*(q)+1][1] = MF(A1, bfr[1][s], acc[2*(q)+1][1]);            \
  acc[2*(q)][2]   = MF(A0, bfr[2][s], acc[2*(q)][2]);              \
  acc[2*(q)+1][2] = MF(A1, bfr[2][s], acc[2*(q)+1][2]);            \
  acc[2*(q)][3]   = MF(A0, bfr[3][s], acc[2*(q)][3]);              \
  acc[2*(q)+1][3] = MF(A1, bfr[3][s], acc[2*(q)+1][3]);

#define LGKM(n) asm volatile("s_waitcnt lgkmcnt(" #n ")" ::: "memory"); \
                __builtin_amdgcn_sched_barrier(0)

#define PHASE(q) {                                                              \
    bf16x8 a0 = RD_A(cb, 2 * (q), 0), a1 = RD_A(cb, 2 * (q), 1);                \
    bf16x8 a2 = RD_A(cb, 2 * (q) + 1, 0), a3 = RD_A(cb, 2 * (q) + 1, 1);        \
    if (t + 2 < NT) { STAGE_A(t + 2, (q) - 1, cb); STAGE_B(t + 2, (q) - 1, cb); } \
    if ((q) == 3) {                                                             \
      if (t < NT - 2) asm volatile("s_waitcnt vmcnt(6)" ::: "memory");          \
      else            asm volatile("s_waitcnt vmcnt(0)" ::: "memory");          \
    }                                                                           \
    __builtin_amdgcn_s_barrier();                                               \
    asm volatile("s_waitcnt lgkmcnt(0)" ::: "memory");                          \
    __builtin_amdgcn_s_setprio(1);                                              \
    MFMA8(2 * (q), a0, a1);                                                     \
    MFMA8(2 * (q) + 1, a2, a3);                                                 \
    __builtin_amdgcn_s_setprio(0);                                              \
    __builtin_amdgcn_s_barrier();                                               \
  }

__global__ __launch_bounds__(512, 2) void gemm_lse(const unsigned short* __restrict__ xb,
                                                   const unsigned short* __restrict__ wt,
                                                   const int* __restrict__ labels,
                                                   float* __restrict__ partial,
                                                   float* __restrict__ tgt,
                                                   int c0, int nbx) {
  __shared__ unsigned short Al[2][256 * 64];
  __shared__ unsigned short Bl[2][256 * 64];
  __shared__ int larr[256];

  const int tid = threadIdx.x;
  const int w = tid >> 6, l = tid & 63;
  const int wm = w >> 2, wn = w & 3;

  // bijective XCD swizzle (nwg = nbx*8, always %8==0); 8 consecutive share B-panel
  const int nwg = nbx * 8;
  const int swz = (blockIdx.x & 7) * (nwg >> 3) + (blockIdx.x >> 3);
  const int m0 = (swz & 7) * 256;
  const int n0 = (swz >> 3) * 256;   // chunk-local
  const int gn0 = c0 + n0;           // global vocab col base

  const int lr = l >> 3;
  const int sw8 = ((l & 7) ^ lr) * 8;

  f32x4 acc[8][4] = {};
  bf16x8 bfr[4][2];

  if (tid < 256) larr[tid] = labels[m0 + tid];

  // prologue: tile0 fully + tile1 quarters/issues 0-2
  STAGE_A(0, 0, 0); STAGE_A(0, 1, 0); STAGE_A(0, 2, 0); STAGE_A(0, 3, 0);
  STAGE_B(0, 0, 0); STAGE_B(0, 1, 0); STAGE_B(0, 2, 0); STAGE_B(0, 3, 0);
  STAGE_A(1, 0, 1); STAGE_B(1, 0, 1);
  STAGE_A(1, 1, 1); STAGE_B(1, 1, 1);
  STAGE_A(1, 2, 1); STAGE_B(1, 2, 1);
  asm volatile("s_waitcnt vmcnt(6)" ::: "memory");
  __builtin_amdgcn_s_barrier();

#pragma unroll 1
  for (int t = 0; t < NT; ++t) {
    const int cb = t & 1;
    // ---- phase 0 (split): [B s0 + A q0 s0] ... [B s1 + A q0 s1] ----
    {
      bfr[0][0] = RD_B(cb, 0, 0); bfr[1][0] = RD_B(cb, 1, 0);
      bfr[2][0] = RD_B(cb, 2, 0); bfr[3][0] = RD_B(cb, 3, 0);
      bf16x8 a0 = RD_A(cb, 0, 0), a2 = RD_A(cb, 1, 0);
      __builtin_amdgcn_sched_barrier(0);  // keep s0 group first in issue order
      bfr[0][1] = RD_B(cb, 0, 1); bfr[1][1] = RD_B(cb, 1, 1);
      bfr[2][1] = RD_B(cb, 2, 1); bfr[3][1] = RD_B(cb, 3, 1);
      bf16x8 a1 = RD_A(cb, 0, 1), a3 = RD_A(cb, 1, 1);
      if (t + 1 < NT) { STAGE_A(t + 1, 3, cb ^ 1); STAGE_B(t + 1, 3, cb ^ 1); }
      __builtin_amdgcn_s_barrier();
      LGKM(6);  // s0 group (6 reads) retired; s1 group completes under s0 MFMAs
      __builtin_amdgcn_s_setprio(1);
      MFMA_HALF(0, 0, a0, a2);
      LGKM(0);
      MFMA_HALF(0, 1, a1, a3);
      __builtin_amdgcn_s_setprio(0);
      __builtin_amdgcn_s_barrier();
    }
    PHASE(1)
    PHASE(2)
    PHASE(3)
  }

  // ---- target extraction: thread slot (mi,ni,r) owns logit[row][col] ----
  // row = m0 + wm*128 + mi*16 + (l>>4)*4 + r ; col = gn0 + wn*64 + ni*16 + (l&15)
  {
    const int colbase = wn * 64 + (l & 15);
#pragma unroll
    for (int mi = 0; mi < 8; ++mi)
#pragma unroll
      for (int r = 0; r < 4; ++r) {
        const int row = wm * 128 + mi * 16 + (l >> 4) * 4 + r;
        int lab = larr[row];
        lab = lab < 0 ? 0 : (lab >= V_DIM ? V_DIM - 1 : lab);
        const int cl = lab - gn0;
#pragma unroll
        for (int ni = 0; ni < 4; ++ni)
          if (cl == colbase + ni * 16) tgt[m0 + row] = acc[mi][ni][r];
      }
  }

  // ---- epilogue: per-row sum of exp over this block's 256 cols ----
  float rs[8][4];
#pragma unroll
  for (int mi = 0; mi < 8; ++mi)
#pragma unroll
    for (int r = 0; r < 4; ++r) {
      float s = 0.f;
#pragma unroll
      for (int ni = 0; ni < 4; ++ni)
        s += exp2f(acc[mi][ni][r] * 1.4426950408889634f);
#pragma unroll
      for (int off = 1; off <= 8; off <<= 1) s += __shfl_xor(s, off, 64);
      rs[mi][r] = s;
    }
  __syncthreads();
  float* red = (float*)&Al[0][0];  // [4 wn][256 rows]
  if ((l & 15) == 0) {
#pragma unroll
    for (int mi = 0; mi < 8; ++mi)
#pragma unroll
      for (int r = 0; r < 4; ++r)
        red[wn * 256 + wm * 128 + mi * 16 + (l >> 4) * 4 + r] = rs[mi][r];
  }
  __syncthreads();
  if (tid < 256) {
    const float tot = (red[tid] + red[256 + tid]) + (red[512 + tid] + red[768 + tid]);
    partial[(size_t)(m0 + tid) * NPB + (c0 / 256 + (swz >> 3))] = tot;
  }
}

// ---------------- final reduce ----------------
__global__ __launch_bounds__(256) void reduce_lse(const float* __restrict__ partial,
                                                  const float* __restrict__ tgt,
                                                  const int* __restrict__ labels,
                                                  float* __restrict__ out) {
  const int row = blockIdx.x;
  float s = 0.f;
  for (int vb = threadIdx.x; vb < NPB; vb += 256)
    s += partial[(size_t)row * NPB + vb];
#pragma unroll
  for (int off = 1; off < 64; off <<= 1) s += __shfl_xor(s, off, 64);
  __shared__ float w4[4];
  if ((threadIdx.x & 63) == 0) w4[threadIdx.x >> 6] = s;
  __syncthreads();
  if (threadIdx.x == 0) {
    const float tot = (w4[0] + w4[1]) + (w4[2] + w4[3]);
    const float lse = logf(tot);
    const float loss = (labels[row] != -100) ? (lse - tgt[row]) : 0.f;
    out[row] = loss;
    out[M_DIM + row] = lse;
  }
}

extern "C" void kernel_launch(void* const* d_in, const int* in_sizes, int n_in,
                              void* d_out, int out_size, void* d_ws, size_t ws_size,
                              hipStream_t stream) {
  const float* x = (const float*)d_in[0];
  const float* wgt = (const float*)d_in[1];
  const int* labels = (const int*)d_in[2];
  float* out = (float*)d_out;

  char* ws = (char*)d_ws;
  unsigned short* xb = (unsigned short*)ws;
  size_t off = (size_t)M_DIM * K_DIM * 2;
  float* partial = (float*)(ws + off);
  off += (size_t)M_DIM * NPB * 4;
  float* tgt = (float*)(ws + off);
  off += (size_t)M_DIM * 4;
  off = (off + 255) & ~(size_t)255;
  unsigned short* wtc = (unsigned short*)(ws + off);
  const size_t avail = ws_size > off ? ws_size - off : 0;
  // CC=16384 (64 MB wtc chunk): stays LLC-resident between transpose and gemm.
  // Full-V (525 MB) measured +270 us on gemm (HBM-latency-bound B loads).
  int CC = 16384;
  while (CC > 256 && (size_t)CC * K_DIM * 2 > avail) CC >>= 1;

  cvt_x<<<dim3(M_DIM * K_DIM / (256 * 8)), dim3(256), 0, stream>>>(x, xb);
  for (int c0 = 0; c0 < V_DIM; c0 += CC) {
    int cc = V_DIM - c0;
    if (cc > CC) cc = CC;
    transpose_w<<<dim3(cc / 64, K_DIM / 64), dim3(256), 0, stream>>>(wgt, wtc, c0);
    const int nbx = cc / 256;
    gemm_lse<<<dim3(nbx * 8), dim3(512), 0, stream>>>(xb, wtc, labels, partial, tgt,
                                                      c0, nbx);
  }
  reduce_lse<<<dim3(M_DIM), dim3(256), 0, stream>>>(partial, tgt, labels, out);
}